// Round 2
// baseline (341.832 us; speedup 1.0000x reference)
//
#include <hip/hip_runtime.h>
#include <hip/hip_bf16.h>

typedef float f32x4 __attribute__((ext_vector_type(4)));
typedef short s16x8 __attribute__((ext_vector_type(8)));

typedef const __attribute__((address_space(1))) unsigned int* gas1_t;
typedef __attribute__((address_space(3))) unsigned int* las3_t;

__device__ __forceinline__ void load_lds16(const void* g, void* l) {
  __builtin_amdgcn_global_load_lds((gas1_t)g, (las3_t)l, 16, 0, 0);
}

__device__ __forceinline__ unsigned short f2bf(float f) {
  union { float f; unsigned u; } v; v.f = f;
  unsigned u = v.u;
  u += 0x7fffu + ((u >> 16) & 1u);   // round-to-nearest-even
  return (unsigned short)(u >> 16);
}

// ---------------- LayerNorm (f32 in, bf16 out), one row (1024) per block ----------------
__global__ __launch_bounds__(256) void ln_bf16_kernel(
    const float* __restrict__ x, const float* __restrict__ w,
    const float* __restrict__ b, unsigned short* __restrict__ out) {
  int row = blockIdx.x;
  int tid = threadIdx.x;
  const float4* xr = (const float4*)(x + (size_t)row * 1024);
  float4 v = xr[tid];
  float s  = v.x + v.y + v.z + v.w;
  float ss = v.x * v.x + v.y * v.y + v.z * v.z + v.w * v.w;
  #pragma unroll
  for (int off = 32; off; off >>= 1) {
    s  += __shfl_down(s, off);
    ss += __shfl_down(ss, off);
  }
  __shared__ float red[8];
  int wid = tid >> 6, lane = tid & 63;
  if (lane == 0) { red[wid] = s; red[wid + 4] = ss; }
  __syncthreads();
  s  = red[0] + red[1] + red[2] + red[3];
  ss = red[4] + red[5] + red[6] + red[7];
  float mu  = s * (1.0f / 1024.0f);
  float var = ss * (1.0f / 1024.0f) - mu * mu;
  float rstd = rsqrtf(var + 1e-5f);
  float4 wv = ((const float4*)w)[tid];
  float4 bv = ((const float4*)b)[tid];
  ushort4 o;
  o.x = f2bf((v.x - mu) * rstd * wv.x + bv.x);
  o.y = f2bf((v.y - mu) * rstd * wv.y + bv.y);
  o.z = f2bf((v.z - mu) * rstd * wv.z + bv.z);
  o.w = f2bf((v.w - mu) * rstd * wv.w + bv.w);
  ((ushort4*)(out + (size_t)row * 1024))[tid] = o;
}

// ---------------- f32 -> bf16 convert (weights) ----------------
__global__ __launch_bounds__(256) void cvt_bf16_kernel(
    const float* __restrict__ in, unsigned short* __restrict__ out) {
  int i = blockIdx.x * 256 + threadIdx.x;
  float4 v = ((const float4*)in)[i];
  ushort4 o;
  o.x = f2bf(v.x); o.y = f2bf(v.y); o.z = f2bf(v.z); o.w = f2bf(v.w);
  ((ushort4*)out)[i] = o;
}

// ---------------- NT GEMM: C[i,j] = sum_k A[i,k]*B[j,k] + bias[j], bf16 out ----------------
// TRANS==0: C row-major M x 1024.
// TRANS==1: per-batch transposed write Ct[b][col][k] (b = row>>10, k = row&1023),
//           used for V so attention can load V^T fragments directly from global.
template <int TRANS>
__global__ __launch_bounds__(256) void gemm_nt_bias_kernel(
    const unsigned short* __restrict__ A, const unsigned short* __restrict__ B,
    const float* __restrict__ bias, unsigned short* __restrict__ C, int M) {
  __shared__ unsigned short As[128 * 32];
  __shared__ unsigned short Bs[128 * 32];
  const int K = 1024, N = 1024;
  int tid = threadIdx.x, lane = tid & 63, wid = tid >> 6;
  int row0 = blockIdx.x * 128, col0 = blockIdx.y * 128;
  int wr = wid >> 1, wc = wid & 1;
  int l15 = lane & 15, kof = (lane >> 4) * 8;
  f32x4 acc[4][4] = {};
  for (int kt = 0; kt < K; kt += 32) {
    #pragma unroll
    for (int r = 0; r < 2; ++r) {
      int ch = wid * 64 + lane + r * 256;
      int rrow = ch >> 2, cc = ch & 3;
      load_lds16(&A[(size_t)(row0 + rrow) * K + kt + cc * 8], &As[ch * 8]);
      load_lds16(&B[(size_t)(col0 + rrow) * K + kt + cc * 8], &Bs[ch * 8]);
    }
    __syncthreads();
    s16x8 af[4], bfr[4];
    #pragma unroll
    for (int m = 0; m < 4; ++m)
      af[m] = *(const s16x8*)&As[(wr * 64 + m * 16 + l15) * 32 + kof];
    #pragma unroll
    for (int n = 0; n < 4; ++n)
      bfr[n] = *(const s16x8*)&Bs[(wc * 64 + n * 16 + l15) * 32 + kof];
    #pragma unroll
    for (int m = 0; m < 4; ++m)
      #pragma unroll
      for (int n = 0; n < 4; ++n)
        acc[m][n] = __builtin_amdgcn_mfma_f32_16x16x32_bf16(af[m], bfr[n], acc[m][n], 0, 0, 0);
    __syncthreads();
  }
  int lg = lane >> 4;
  if (TRANS) {
    int b = row0 >> 10;
    int kbase = (row0 & 1023) + wr * 64 + lg * 4;
    #pragma unroll
    for (int n = 0; n < 4; ++n) {
      int col = col0 + wc * 64 + n * 16 + l15;
      float bb = bias[col];
      unsigned short* cp = C + (size_t)b * 1048576 + (size_t)col * 1024 + kbase;
      #pragma unroll
      for (int m = 0; m < 4; ++m) {
        ushort4 o;
        o.x = f2bf(acc[m][n][0] + bb);
        o.y = f2bf(acc[m][n][1] + bb);
        o.z = f2bf(acc[m][n][2] + bb);
        o.w = f2bf(acc[m][n][3] + bb);
        *(ushort4*)(cp + m * 16) = o;
      }
    }
  } else {
    #pragma unroll
    for (int n = 0; n < 4; ++n) {
      int col = col0 + wc * 64 + n * 16 + l15;
      float bb = bias[col];
      #pragma unroll
      for (int m = 0; m < 4; ++m) {
        #pragma unroll
        for (int j = 0; j < 4; ++j) {
          int row = row0 + wr * 64 + m * 16 + lg * 4 + j;
          C[(size_t)row * N + col] = f2bf(acc[m][n][j] + bb);
        }
      }
    }
  }
}

// ---------------- Fused sigmoid cross-attention ----------------
// grid: 128 blocks; bid -> (b = bid&7, qt = bid>>3) so all 16 q-tiles of a batch
// land on one XCD (round-robin dispatch %8) and K/V stay in that XCD's L2.
// block: 1024 threads = 16 waves, wave h = head h, QBLK=32 q-rows, KVBLK=32.
// K and V^T fragments are loaded DIRECTLY global->register (no LDS staging);
// LDS holds only P (for QK->PV layout transpose + head-mean), stride-padded.
#define PSTR 40  // u16 per q-row: 80 B (16B-aligned, bank-spread)
__global__ __launch_bounds__(1024, 4) void attn_kernel(
    const unsigned short* __restrict__ Q, const unsigned short* __restrict__ K,
    const unsigned short* __restrict__ Vt, float* __restrict__ out,
    float* __restrict__ meanout) {
  __shared__ unsigned short Plds[16 * 32 * PSTR];  // 40 KB
  int bid = blockIdx.x;
  int b = bid & 7, qt = bid >> 3;
  int q0 = qt * 32;
  int tid = threadIdx.x, lane = tid & 63, h = tid >> 6;
  int l15 = lane & 15, lg = lane >> 4;

  const unsigned short* Qp = Q + (size_t)(b * 512 + q0) * 1024 + h * 64;
  const unsigned short* Kp = K + (size_t)b * 1048576 + h * 64;
  const unsigned short* Vp = Vt + (size_t)b * 1048576 + (size_t)(h * 64) * 1024;

  // Q A-frags (reused all key-tiles): row=q=lane&15, k=(lane>>4)*8+j
  s16x8 aq[2][2];
  #pragma unroll
  for (int m = 0; m < 2; ++m)
    #pragma unroll
    for (int ks = 0; ks < 2; ++ks)
      aq[m][ks] = *(const s16x8*)(Qp + (size_t)(m * 16 + l15) * 1024 + ks * 32 + lg * 8);

  f32x4 oacc[2][4] = {};
  unsigned short* Ph = Plds + h * (32 * PSTR);

  for (int kt = 0; kt < 1024; kt += 32) {
    // S = Q K^T : B-frag K[key=l15][d=lg*8..] straight from global
    f32x4 s[2][2] = {};
    {
      s16x8 bk[2][2];
      #pragma unroll
      for (int kc = 0; kc < 2; ++kc)
        #pragma unroll
        for (int ks = 0; ks < 2; ++ks)
          bk[kc][ks] = *(const s16x8*)(Kp + (size_t)(kt + kc * 16 + l15) * 1024 + ks * 32 + lg * 8);
      #pragma unroll
      for (int m = 0; m < 2; ++m)
        #pragma unroll
        for (int kc = 0; kc < 2; ++kc) {
          s[m][kc] = __builtin_amdgcn_mfma_f32_16x16x32_bf16(aq[m][0], bk[kc][0], s[m][kc], 0, 0, 0);
          s[m][kc] = __builtin_amdgcn_mfma_f32_16x16x32_bf16(aq[m][1], bk[kc][1], s[m][kc], 0, 0, 0);
        }
    }
    // V B-frags for PV: Vt[d=l15][key=lg*8..] straight from global;
    // issued here so HBM/L2 latency hides under sigmoid + P-store + barrier + mean.
    s16x8 bv[4];
    #pragma unroll
    for (int nd = 0; nd < 4; ++nd)
      bv[nd] = *(const s16x8*)(Vp + (size_t)(nd * 16 + l15) * 1024 + kt + lg * 8);

    // sigmoid -> P (bf16) into LDS. C-layout: col=key=l15, row=q=lg*4+j.
    #pragma unroll
    for (int m = 0; m < 2; ++m)
      #pragma unroll
      for (int kc = 0; kc < 2; ++kc)
        #pragma unroll
        for (int j = 0; j < 4; ++j) {
          float p = __builtin_amdgcn_rcpf(1.0f + __expf(s[m][kc][j] * -0.125f));
          Ph[(m * 16 + lg * 4 + j) * PSTR + kc * 16 + l15] = f2bf(p);
        }
    __syncthreads();

    // head-mean: 512 threads, each (q, key-pair), sum 16 heads via u32 reads
    if (tid < 512) {
      int q = tid >> 4, kc2 = tid & 15;
      const unsigned short* pp = Plds + q * PSTR + kc2 * 2;
      float s0 = 0.f, s1 = 0.f;
      #pragma unroll
      for (int hh = 0; hh < 16; ++hh) {
        unsigned u = *(const unsigned*)(pp + hh * (32 * PSTR));
        union { unsigned u; float f; } lo, hi;
        lo.u = u << 16; hi.u = u & 0xffff0000u;
        s0 += lo.f; s1 += hi.f;
      }
      float2 mo; mo.x = s0 * 0.0625f; mo.y = s1 * 0.0625f;
      *(float2*)&meanout[(size_t)(b * 512 + q0 + q) * 1024 + kt + kc2 * 2] = mo;
    }

    // O += P V : A-frag P[q=l15][key=lg*8..] (16B-aligned b128 reads)
    s16x8 pa[2];
    pa[0] = *(const s16x8*)(Ph + l15 * PSTR + lg * 8);
    pa[1] = *(const s16x8*)(Ph + (16 + l15) * PSTR + lg * 8);
    #pragma unroll
    for (int m = 0; m < 2; ++m)
      #pragma unroll
      for (int nd = 0; nd < 4; ++nd)
        oacc[m][nd] = __builtin_amdgcn_mfma_f32_16x16x32_bf16(pa[m], bv[nd], oacc[m][nd], 0, 0, 0);
    __syncthreads();
  }

  // write O (f32): row=q=lg*4+j, col=d=l15 within 16-wide slice
  #pragma unroll
  for (int m = 0; m < 2; ++m)
    #pragma unroll
    for (int nd = 0; nd < 4; ++nd)
      #pragma unroll
      for (int j = 0; j < 4; ++j) {
        int q = m * 16 + lg * 4 + j, d = h * 64 + nd * 16 + l15;
        out[(size_t)(b * 512 + q0 + q) * 1024 + d] = oacc[m][nd][j];
      }
}

extern "C" void kernel_launch(void* const* d_in, const int* in_sizes, int n_in,
                              void* d_out, int out_size, void* d_ws, size_t ws_size,
                              hipStream_t stream) {
  const float* text = (const float*)d_in[0];   // 8*512*1024
  const float* av   = (const float*)d_in[1];   // 8*1024*1024
  const float* tn_w = (const float*)d_in[2];
  const float* tn_b = (const float*)d_in[3];
  const float* an_w = (const float*)d_in[4];
  const float* an_b = (const float*)d_in[5];
  const float* Wq   = (const float*)d_in[6];
  const float* bq   = (const float*)d_in[7];
  const float* Wk   = (const float*)d_in[8];
  const float* bk   = (const float*)d_in[9];
  const float* Wv   = (const float*)d_in[10];
  const float* bv   = (const float*)d_in[11];

  char* ws = (char*)d_ws;
  const size_t MB = 1u << 20;
  unsigned short* Wqb = (unsigned short*)(ws + 0 * MB);    // 2 MB
  unsigned short* Wkb = (unsigned short*)(ws + 2 * MB);    // 2 MB
  unsigned short* Wvb = (unsigned short*)(ws + 4 * MB);    // 2 MB
  unsigned short* Tln = (unsigned short*)(ws + 6 * MB);    // 8 MB  (4096x1024)
  unsigned short* Aln = (unsigned short*)(ws + 14 * MB);   // 16 MB (8192x1024)
  unsigned short* Qb  = (unsigned short*)(ws + 30 * MB);   // 8 MB
  unsigned short* Kb  = (unsigned short*)(ws + 38 * MB);   // 16 MB
  unsigned short* Vtb = (unsigned short*)(ws + 54 * MB);   // 16 MB transposed V (end: 70 MB)

  float* out  = (float*)d_out;
  float* mout = out + (size_t)8 * 512 * 1024;

  ln_bf16_kernel<<<4096, 256, 0, stream>>>(text, tn_w, tn_b, Tln);
  ln_bf16_kernel<<<8192, 256, 0, stream>>>(av, an_w, an_b, Aln);
  cvt_bf16_kernel<<<1024, 256, 0, stream>>>(Wq, Wqb);
  cvt_bf16_kernel<<<1024, 256, 0, stream>>>(Wk, Wkb);
  cvt_bf16_kernel<<<1024, 256, 0, stream>>>(Wv, Wvb);
  dim3 gq(32, 8), gk(64, 8);
  gemm_nt_bias_kernel<0><<<gq, 256, 0, stream>>>(Tln, Wqb, bq, Qb, 4096);
  gemm_nt_bias_kernel<0><<<gk, 256, 0, stream>>>(Aln, Wkb, bk, Kb, 8192);
  gemm_nt_bias_kernel<1><<<gk, 256, 0, stream>>>(Aln, Wvb, bv, Vtb, 8192);
  attn_kernel<<<128, 1024, 0, stream>>>(Qb, Kb, Vtb, out, mout);
}

// Round 3
// 323.143 us; speedup vs baseline: 1.0578x; 1.0578x over previous
//
#include <hip/hip_runtime.h>
#include <hip/hip_bf16.h>
#include <math.h>

typedef float f32x4 __attribute__((ext_vector_type(4)));
typedef short s16x8 __attribute__((ext_vector_type(8)));
typedef unsigned short us;

typedef const __attribute__((address_space(1))) unsigned int* gas1_t;
typedef __attribute__((address_space(3))) unsigned int* las3_t;

__device__ __forceinline__ void load_lds16(const void* g, void* l) {
  __builtin_amdgcn_global_load_lds((gas1_t)g, (las3_t)l, 16, 0, 0);
}

__device__ __forceinline__ us f2bf(float f) {
  union { float f; unsigned u; } v; v.f = f;
  unsigned u = v.u;
  u += 0x7fffu + ((u >> 16) & 1u);   // RNE
  return (us)(u >> 16);
}

// ---------------- prep: LayerNorm rows (text, av) + weight f32->bf16 converts ----------------
// grid: [0,4096) text LN rows; [4096,12288) av LN rows; [12288,15360) cvt chunks.
__global__ __launch_bounds__(256) void prep_kernel(
    const float* __restrict__ text, const float* __restrict__ av,
    const float* __restrict__ tn_w, const float* __restrict__ tn_b,
    const float* __restrict__ an_w, const float* __restrict__ an_b,
    const float* __restrict__ Wq, const float* __restrict__ Wk, const float* __restrict__ Wv,
    us* __restrict__ Tln, us* __restrict__ Aln,
    us* __restrict__ Wqb, us* __restrict__ Wkb, us* __restrict__ Wvb) {
  int id = blockIdx.x, tid = threadIdx.x;
  if (id >= 12288) {                       // weight convert
    int c = id - 12288;
    const float* src; us* dst;
    if (c < 1024)      { src = Wq; dst = Wqb; }
    else if (c < 2048) { src = Wk; dst = Wkb; c -= 1024; }
    else               { src = Wv; dst = Wvb; c -= 2048; }
    int i = c * 256 + tid;
    float4 v = ((const float4*)src)[i];
    ushort4 o;
    o.x = f2bf(v.x); o.y = f2bf(v.y); o.z = f2bf(v.z); o.w = f2bf(v.w);
    ((ushort4*)dst)[i] = o;
    return;
  }
  const float *x, *w, *b; us* outp; int row;
  if (id < 4096) { x = text; w = tn_w; b = tn_b; outp = Tln; row = id; }
  else           { x = av;   w = an_w; b = an_b; outp = Aln; row = id - 4096; }
  const float4* xr = (const float4*)(x + (size_t)row * 1024);
  float4 v = xr[tid];
  float s  = v.x + v.y + v.z + v.w;
  float ss = v.x * v.x + v.y * v.y + v.z * v.z + v.w * v.w;
  #pragma unroll
  for (int off = 32; off; off >>= 1) {
    s  += __shfl_down(s, off);
    ss += __shfl_down(ss, off);
  }
  __shared__ float red[8];
  int wid = tid >> 6, lane = tid & 63;
  if (lane == 0) { red[wid] = s; red[wid + 4] = ss; }
  __syncthreads();
  s  = red[0] + red[1] + red[2] + red[3];
  ss = red[4] + red[5] + red[6] + red[7];
  float mu  = s * (1.0f / 1024.0f);
  float var = ss * (1.0f / 1024.0f) - mu * mu;
  float rstd = rsqrtf(var + 1e-5f);
  float4 wv = ((const float4*)w)[tid];
  float4 bv = ((const float4*)b)[tid];
  ushort4 o;
  o.x = f2bf((v.x - mu) * rstd * wv.x + bv.x);
  o.y = f2bf((v.y - mu) * rstd * wv.y + bv.y);
  o.z = f2bf((v.z - mu) * rstd * wv.z + bv.z);
  o.w = f2bf((v.w - mu) * rstd * wv.w + bv.w);
  ((ushort4*)(outp + (size_t)row * 1024))[tid] = o;
}

// ---------------- fused triple NT-GEMM, 2-phase double-buffered LDS ----------------
// C[i,j] = sum_k A[i,k]*B[j,k] + bias[j].  K=N=1024, BK=32, 128x128 tile, 4 waves.
// grid: [0,256) Q (M=4096); [256,768) K (M=8192); [768,1280) V (M=8192, transposed write).
__global__ __launch_bounds__(256) void gemm3_kernel(
    const us* __restrict__ Tln, const us* __restrict__ Aln,
    const us* __restrict__ Wqb, const us* __restrict__ Wkb, const us* __restrict__ Wvb,
    const float* __restrict__ bq, const float* __restrict__ bk_, const float* __restrict__ bv_,
    us* __restrict__ Qb, us* __restrict__ Kb, us* __restrict__ Vtb) {
  __shared__ us As[2][128 * 32];
  __shared__ us Bs[2][128 * 32];
  const int K = 1024, N = 1024;
  int id = blockIdx.x;
  const us *A, *B; const float* bias; us* C; bool trans = false;
  int rb, cb;
  if (id < 256)      { A = Tln; B = Wqb; bias = bq;  C = Qb;  rb = id >> 3; cb = id & 7; }
  else if (id < 768) { id -= 256; A = Aln; B = Wkb; bias = bk_; C = Kb; rb = id >> 3; cb = id & 7; }
  else               { id -= 768; A = Aln; B = Wvb; bias = bv_; C = Vtb; rb = id >> 3; cb = id & 7; trans = true; }
  int row0 = rb * 128, col0 = cb * 128;
  int tid = threadIdx.x, lane = tid & 63, wid = tid >> 6;
  int wr = wid >> 1, wc = wid & 1;
  int l15 = lane & 15, kof = (lane >> 4) * 8, lg = lane >> 4;
  // stage addressing (wave-uniform base + lane)
  int ch0 = wid * 64 + lane, ch1 = ch0 + 256;
  int r0 = ch0 >> 2, c0 = ch0 & 3, r1 = ch1 >> 2, c1 = ch1 & 3;

#define G3_STAGE(buf, kt)                                                       \
  { load_lds16(&A[(size_t)(row0 + r0) * K + (kt) + c0 * 8], &As[buf][ch0 * 8]); \
    load_lds16(&B[(size_t)(col0 + r0) * K + (kt) + c0 * 8], &Bs[buf][ch0 * 8]); \
    load_lds16(&A[(size_t)(row0 + r1) * K + (kt) + c1 * 8], &As[buf][ch1 * 8]); \
    load_lds16(&B[(size_t)(col0 + r1) * K + (kt) + c1 * 8], &Bs[buf][ch1 * 8]); }

  f32x4 acc[4][4] = {};
  G3_STAGE(0, 0);
  __syncthreads();
  int cur = 0;
  for (int kt = 0; kt < K; kt += 32) {
    if (kt + 32 < K) G3_STAGE(cur ^ 1, kt + 32);
    s16x8 af[4], bfr[4];
    #pragma unroll
    for (int m = 0; m < 4; ++m)
      af[m] = *(const s16x8*)&As[cur][(wr * 64 + m * 16 + l15) * 32 + kof];
    #pragma unroll
    for (int n = 0; n < 4; ++n)
      bfr[n] = *(const s16x8*)&Bs[cur][(wc * 64 + n * 16 + l15) * 32 + kof];
    #pragma unroll
    for (int m = 0; m < 4; ++m)
      #pragma unroll
      for (int n = 0; n < 4; ++n)
        acc[m][n] = __builtin_amdgcn_mfma_f32_16x16x32_bf16(af[m], bfr[n], acc[m][n], 0, 0, 0);
    __syncthreads();   // drains vmcnt (next buf staged) + lgkmcnt
    cur ^= 1;
  }
  if (trans) {
    int b = row0 >> 10;
    int kbase = (row0 & 1023) + wr * 64 + lg * 4;
    #pragma unroll
    for (int n = 0; n < 4; ++n) {
      int col = col0 + wc * 64 + n * 16 + l15;
      float bb = bias[col];
      us* cp = C + (size_t)b * 1048576 + (size_t)col * 1024 + kbase;
      #pragma unroll
      for (int m = 0; m < 4; ++m) {
        ushort4 o;
        o.x = f2bf(acc[m][n][0] + bb);
        o.y = f2bf(acc[m][n][1] + bb);
        o.z = f2bf(acc[m][n][2] + bb);
        o.w = f2bf(acc[m][n][3] + bb);
        *(ushort4*)(cp + m * 16) = o;
      }
    }
  } else {
    #pragma unroll
    for (int n = 0; n < 4; ++n) {
      int col = col0 + wc * 64 + n * 16 + l15;
      float bb = bias[col];
      #pragma unroll
      for (int m = 0; m < 4; ++m)
        #pragma unroll
        for (int j = 0; j < 4; ++j) {
          int row = row0 + wr * 64 + m * 16 + lg * 4 + j;
          C[(size_t)row * N + col] = f2bf(acc[m][n][j] + bb);
        }
    }
  }
#undef G3_STAGE
}

// ---------------- Fused sigmoid cross-attention ----------------
// grid: 256 blocks, bid = qt*8 + b (batch pinned to one XCD). block: 16 waves = 16 heads.
// QBLK=16 q-rows, KVBLK=32. K/V frags direct global->reg; K double-buffered in regs
// (prefetch t+1), V issued at iteration top / consumed after barrier. P double-buffered
// in LDS -> ONE barrier per key-tile.
#define PSTR 40                  // u16 per q-row (80 B, 16B-aligned)
#define PBUF (16 * 16 * PSTR)    // u16 per buffer (16 heads x 16 q)
__global__ __launch_bounds__(1024, 4) void attn_kernel(
    const us* __restrict__ Q, const us* __restrict__ K,
    const us* __restrict__ Vt, float* __restrict__ out,
    float* __restrict__ meanout) {
  __shared__ us Plds[2 * PBUF];  // 40 KB
  int bid = blockIdx.x;
  int b = bid & 7, qt = bid >> 3;
  int q0 = qt * 16;
  int tid = threadIdx.x, lane = tid & 63, h = tid >> 6;
  int l15 = lane & 15, lg = lane >> 4;

  const us* Qp = Q + (size_t)(b * 512 + q0) * 1024 + h * 64;
  const us* Kp = K + (size_t)b * 1048576 + h * 64;
  const us* Vp = Vt + (size_t)b * 1048576 + (size_t)(h * 64) * 1024;

  // Q A-frags: row=q=lane&15, k=(lane>>4)*8+j
  s16x8 aq0 = *(const s16x8*)(Qp + (size_t)l15 * 1024 + lg * 8);
  s16x8 aq1 = *(const s16x8*)(Qp + (size_t)l15 * 1024 + 32 + lg * 8);

  f32x4 oacc[4] = {};
  const float SC = -0.1803368801111244f;  // -(1/8)*log2(e)
  const us* Kl = Kp + (size_t)l15 * 1024 + lg * 8;       // kc=0 base (key=l15)
  const us* Vl = Vp + (size_t)l15 * 1024 + lg * 8;       // nd=0 base (d=l15)

  s16x8 bkA[2][2], bkB[2][2];
  #pragma unroll
  for (int kc = 0; kc < 2; ++kc)
    #pragma unroll
    for (int ks = 0; ks < 2; ++ks)
      bkA[kc][ks] = *(const s16x8*)(Kl + (size_t)(kc * 16) * 1024 + ks * 32);

#define ATTN_STEP(KT, BKU, BKP, BUF)                                              \
  {                                                                               \
    /* V B-frags for this tile (consumed after barrier) */                        \
    s16x8 bvv[4];                                                                 \
    _Pragma("unroll")                                                             \
    for (int nd = 0; nd < 4; ++nd)                                                \
      bvv[nd] = *(const s16x8*)(Vl + (size_t)(nd * 16) * 1024 + (KT));            \
    /* S = Q K^T */                                                               \
    f32x4 s0 = {}, s1 = {};                                                       \
    s0 = __builtin_amdgcn_mfma_f32_16x16x32_bf16(aq0, BKU[0][0], s0, 0, 0, 0);    \
    s0 = __builtin_amdgcn_mfma_f32_16x16x32_bf16(aq1, BKU[0][1], s0, 0, 0, 0);    \
    s1 = __builtin_amdgcn_mfma_f32_16x16x32_bf16(aq0, BKU[1][0], s1, 0, 0, 0);    \
    s1 = __builtin_amdgcn_mfma_f32_16x16x32_bf16(aq1, BKU[1][1], s1, 0, 0, 0);    \
    /* prefetch next tile's K frags */                                            \
    if ((KT) + 32 < 1024) {                                                       \
      _Pragma("unroll")                                                           \
      for (int kc = 0; kc < 2; ++kc)                                              \
        _Pragma("unroll")                                                         \
        for (int ks = 0; ks < 2; ++ks)                                            \
          BKP[kc][ks] = *(const s16x8*)(Kl + (size_t)((KT) + 32 + kc * 16) * 1024 + ks * 32); \
    }                                                                             \
    /* sigmoid -> P bf16 into LDS buf */                                          \
    us* Ph = Plds + (BUF) * PBUF + h * (16 * PSTR);                               \
    _Pragma("unroll")                                                             \
    for (int j = 0; j < 4; ++j) {                                                 \
      float p0 = __builtin_amdgcn_rcpf(1.0f + exp2f(s0[j] * SC));                 \
      float p1 = __builtin_amdgcn_rcpf(1.0f + exp2f(s1[j] * SC));                 \
      Ph[(lg * 4 + j) * PSTR + l15]      = f2bf(p0);                              \
      Ph[(lg * 4 + j) * PSTR + 16 + l15] = f2bf(p1);                              \
    }                                                                             \
    __syncthreads();                                                              \
    /* head-mean: 256 threads, each (q, u32-pair), sum 16 heads */                \
    if (tid < 256) {                                                              \
      int q = tid >> 4, pr = tid & 15;                                            \
      const us* pp = Plds + (BUF) * PBUF + q * PSTR + pr * 2;                     \
      float m0 = 0.f, m1 = 0.f;                                                   \
      _Pragma("unroll")                                                           \
      for (int hh = 0; hh < 16; ++hh) {                                           \
        unsigned u = *(const unsigned*)(pp + hh * (16 * PSTR));                   \
        union { unsigned u; float f; } lo, hi;                                    \
        lo.u = u << 16; hi.u = u & 0xffff0000u;                                   \
        m0 += lo.f; m1 += hi.f;                                                   \
      }                                                                           \
      float2 mo; mo.x = m0 * 0.0625f; mo.y = m1 * 0.0625f;                        \
      *(float2*)&meanout[(size_t)(b * 512 + q0 + q) * 1024 + (KT) + pr * 2] = mo; \
    }                                                                             \
    /* O += P V */                                                                \
    s16x8 pa = *(const s16x8*)(Ph + l15 * PSTR + lg * 8);                         \
    _Pragma("unroll")                                                             \
    for (int nd = 0; nd < 4; ++nd)                                                \
      oacc[nd] = __builtin_amdgcn_mfma_f32_16x16x32_bf16(pa, bvv[nd], oacc[nd], 0, 0, 0); \
  }

  for (int kt = 0; kt < 1024; kt += 64) {
    ATTN_STEP(kt,      bkA, bkB, 0);
    ATTN_STEP(kt + 32, bkB, bkA, 1);
  }
#undef ATTN_STEP

  // write O (f32): row=q=lg*4+j, col=d=l15 within 16-wide slice
  #pragma unroll
  for (int nd = 0; nd < 4; ++nd)
    #pragma unroll
    for (int j = 0; j < 4; ++j) {
      int q = lg * 4 + j, d = h * 64 + nd * 16 + l15;
      out[(size_t)(b * 512 + q0 + q) * 1024 + d] = oacc[nd][j];
    }
}

extern "C" void kernel_launch(void* const* d_in, const int* in_sizes, int n_in,
                              void* d_out, int out_size, void* d_ws, size_t ws_size,
                              hipStream_t stream) {
  const float* text = (const float*)d_in[0];
  const float* av   = (const float*)d_in[1];
  const float* tn_w = (const float*)d_in[2];
  const float* tn_b = (const float*)d_in[3];
  const float* an_w = (const float*)d_in[4];
  const float* an_b = (const float*)d_in[5];
  const float* Wq   = (const float*)d_in[6];
  const float* bq   = (const float*)d_in[7];
  const float* Wk   = (const float*)d_in[8];
  const float* bk   = (const float*)d_in[9];
  const float* Wv   = (const float*)d_in[10];
  const float* bv   = (const float*)d_in[11];

  char* ws = (char*)d_ws;
  const size_t MB = 1u << 20;
  us* Wqb = (us*)(ws + 0 * MB);
  us* Wkb = (us*)(ws + 2 * MB);
  us* Wvb = (us*)(ws + 4 * MB);
  us* Tln = (us*)(ws + 6 * MB);
  us* Aln = (us*)(ws + 14 * MB);
  us* Qb  = (us*)(ws + 30 * MB);
  us* Kb  = (us*)(ws + 38 * MB);
  us* Vtb = (us*)(ws + 54 * MB);

  float* out  = (float*)d_out;
  float* mout = out + (size_t)8 * 512 * 1024;

  prep_kernel<<<15360, 256, 0, stream>>>(text, av, tn_w, tn_b, an_w, an_b,
                                         Wq, Wk, Wv, Tln, Aln, Wqb, Wkb, Wvb);
  gemm3_kernel<<<1280, 256, 0, stream>>>(Tln, Aln, Wqb, Wkb, Wvb,
                                         bq, bk, bv, Qb, Kb, Vtb);
  attn_kernel<<<256, 1024, 0, stream>>>(Qb, Kb, Vtb, out, mout);
}